// Round 14
// baseline (354.859 us; speedup 1.0000x reference)
//
#include <hip/hip_runtime.h>

#define T_STEPS 512
#define HID 128
#define ROWS 16   // batch rows per sequence tile
#define SEQS 2    // independent sequences per block -> 32 blocks

typedef short bf16x8 __attribute__((ext_vector_type(8)));   // MFMA A/B frag
typedef float f32x4  __attribute__((ext_vector_type(4)));   // MFMA C/D frag
typedef unsigned int u32;
typedef u32 u32x4 __attribute__((ext_vector_type(4)));

// 512 threads = 8 waves = 2 waves/SIMD. Wave w owns j-tile [16w, 16w+16) for
// BOTH sequences: 16 MFMA/step-pair (8 hi-chains issued back-to-back, then 8
// dependent lo's -> dep spacing 8 issues > MFMA latency). One barrier per
// step covers both seqs: the fixed latency (barrier + LDS round trip) is
// amortized over 2 steps of work (R13: 933 cyc covered ONE step).

__device__ __forceinline__ u32 cvt_pk_bf16(float s0, float s1) {
    u32 d;  // d.lo = bf16(s0), d.hi = bf16(s1)
    asm("v_cvt_pk_bf16_f32 %0, %1, %2" : "=v"(d) : "v"(s0), "v"(s1));
    return d;
}
__device__ __forceinline__ bf16x8 frag_from(u32 a, u32 b, u32 c, u32 d) {
    u32x4 t = {a, b, c, d};
    return __builtin_bit_cast(bf16x8, t);
}
// tanh(a) = 1 - 2/(exp2(2a*log2e)+1); saturates correctly at +-inf
__device__ __forceinline__ float tanh_fast(float a) {
    const float e  = __builtin_amdgcn_exp2f(a * 2.885390081777926816f);
    const float rc = __builtin_amdgcn_rcpf(e + 1.0f);
    return fmaf(-2.0f, rc, 1.0f);
}

// split 8 f32 into hi/lo bf16 frags (W ~= WH + WL, residual ~2^-18 rel)
#define SPLIT8(HI, LO, fa, fb) do {                                           \
    u32 h0_ = cvt_pk_bf16(fa.x,fa.y), h1_ = cvt_pk_bf16(fa.z,fa.w);           \
    u32 h2_ = cvt_pk_bf16(fb.x,fb.y), h3_ = cvt_pk_bf16(fb.z,fb.w);           \
    float l0_ = fa.x - __uint_as_float(h0_ << 16);                            \
    float l1_ = fa.y - __uint_as_float(h0_ & 0xffff0000u);                    \
    float l2_ = fa.z - __uint_as_float(h1_ << 16);                            \
    float l3_ = fa.w - __uint_as_float(h1_ & 0xffff0000u);                    \
    float l4_ = fb.x - __uint_as_float(h2_ << 16);                            \
    float l5_ = fb.y - __uint_as_float(h2_ & 0xffff0000u);                    \
    float l6_ = fb.z - __uint_as_float(h3_ << 16);                            \
    float l7_ = fb.w - __uint_as_float(h3_ & 0xffff0000u);                    \
    u32 g0_ = cvt_pk_bf16(l0_,l1_), g1_ = cvt_pk_bf16(l2_,l3_);               \
    u32 g2_ = cvt_pk_bf16(l4_,l5_), g3_ = cvt_pk_bf16(l6_,l7_);               \
    HI = frag_from(h0_,h1_,h2_,h3_); LO = frag_from(g0_,g1_,g2_,g3_);         \
} while (0)

#define MFMA(ACC, A, B) \
    ACC = __builtin_amdgcn_mfma_f32_16x16x32_bf16(A, B, ACC, 0, 0, 0);

// LDS: seqA h buf0 @0, buf1 @4096; seqB h buf0 @8192, buf1 @12288
//      ([16 r][128 j] bf16, byte ^= (r&7)<<4); red @16384 ([2 s][8 w][16 r] f32)
#define LDS_BYTES (16384 + 1024)

__global__ __launch_bounds__(512, 1)
__attribute__((amdgpu_waves_per_eu(2, 2)))
void rnn_mfma8x2_kernel(const float* __restrict__ x,
                        const float* __restrict__ W_ih,
                        const float* __restrict__ W_hh,
                        const float* __restrict__ b_ih,
                        const float* __restrict__ b_hh,
                        const float* __restrict__ W_out,
                        const float* __restrict__ b_out,
                        float* __restrict__ y)
{
    __shared__ __align__(16) char lds[LDS_BYTES];

    const int tid = threadIdx.x;
    const int w   = tid >> 6;        // wave 0..7: j-tile [16w, 16w+16)
    const int l   = tid & 63;
    const int q   = l >> 4;          // lane quarter (k-group / C row group)
    const int r   = l & 15;          // batch row (A row m / B col n / C col n)
    const int b0A = blockIdx.x * (SEQS * ROWS);
    const int b0B = b0A + ROWS;

    // ---- zero h buf0 both seqs (512 threads x 8 B each)
    *(uint2*)&lds[tid * 8]        = make_uint2(0u, 0u);
    *(uint2*)&lds[8192 + tid * 8] = make_uint2(0u, 0u);

    // ---- W_hh A-frags for tile w (SHARED between seqs)
    bf16x8 WH0, WH1, WH2, WH3, WL0, WL1, WL2, WL3;
    {
        const float* p = W_hh + (size_t)(16 * w + r) * HID + 8 * q;
        float4 fa, fb;
        fa = *(const float4*)(p +  0); fb = *(const float4*)(p +   4); SPLIT8(WH0, WL0, fa, fb);
        fa = *(const float4*)(p + 32); fb = *(const float4*)(p +  36); SPLIT8(WH1, WL1, fa, fb);
        fa = *(const float4*)(p + 64); fb = *(const float4*)(p +  68); SPLIT8(WH2, WL2, fa, fb);
        fa = *(const float4*)(p + 96); fb = *(const float4*)(p + 100); SPLIT8(WH3, WL3, fa, fb);
    }

    // ---- per-lane constants for this lane's 4 outputs j0..j0+3
    const int j0 = 16 * w + 4 * q;
    const float4 wih = *(const float4*)(W_ih + j0);
    float4 bias;
    {
        const float4 bi = *(const float4*)(b_ih + j0);
        const float4 bh = *(const float4*)(b_hh + j0);
        bias.x = bi.x + bh.x; bias.y = bi.y + bh.y;
        bias.z = bi.z + bh.z; bias.w = bi.w + bh.w;
    }

    // ---- swizzled LDS offsets (relative to seq/parity base)
    const int swz   = (r & 7) << 4;
    const int voff0 = (r*256 + q*16      ) ^ swz;
    const int voff1 = (r*256 + q*16 +  64) ^ swz;
    const int voff2 = (r*256 + q*16 + 128) ^ swz;
    const int voff3 = (r*256 + q*16 + 192) ^ swz;
    const int woff  = (r*256 + 32*w + 8*q) ^ swz;   // h write (8 B)

    const float* __restrict__ xrowA = x + (size_t)(b0A + r) * T_STEPS;
    const float* __restrict__ xrowB = x + (size_t)(b0B + r) * T_STEPS;
    float xtA = xrowA[0], xtB = xrowB[0];
    f32x4 hvA, hvB;

    __syncthreads();

    u32 rbA = 0, wbA = 4096;
    for (int t = 0; t < T_STEPS; ++t) {
        // B-frags, both seqs (8x ds_read_b128)
        const bf16x8 BA0 = *(const bf16x8*)&lds[rbA + voff0];
        const bf16x8 BA1 = *(const bf16x8*)&lds[rbA + voff1];
        const bf16x8 BA2 = *(const bf16x8*)&lds[rbA + voff2];
        const bf16x8 BA3 = *(const bf16x8*)&lds[rbA + voff3];
        const bf16x8 BB0 = *(const bf16x8*)&lds[rbA + 8192 + voff0];
        const bf16x8 BB1 = *(const bf16x8*)&lds[rbA + 8192 + voff1];
        const bf16x8 BB2 = *(const bf16x8*)&lds[rbA + 8192 + voff2];
        const bf16x8 BB3 = *(const bf16x8*)&lds[rbA + 8192 + voff3];

        const int tn = (t < T_STEPS - 1) ? t + 1 : T_STEPS - 1;
        const float xnA = xrowA[tn];
        const float xnB = xrowB[tn];

        f32x4 aA0, aA1, aA2, aA3, aB0, aB1, aB2, aB3;
        aA0[0] = fmaf(xtA, wih.x, bias.x); aA0[1] = fmaf(xtA, wih.y, bias.y);
        aA0[2] = fmaf(xtA, wih.z, bias.z); aA0[3] = fmaf(xtA, wih.w, bias.w);
        aB0[0] = fmaf(xtB, wih.x, bias.x); aB0[1] = fmaf(xtB, wih.y, bias.y);
        aB0[2] = fmaf(xtB, wih.z, bias.z); aB0[3] = fmaf(xtB, wih.w, bias.w);
        aA1 = (f32x4)(0.0f); aA2 = (f32x4)(0.0f); aA3 = (f32x4)(0.0f);
        aB1 = (f32x4)(0.0f); aB2 = (f32x4)(0.0f); aB3 = (f32x4)(0.0f);

        // 16 MFMAs: 8 independent hi's first, then the 8 dependent lo's
        // (dep spacing = 8 issues > MFMA latency)
        MFMA(aA0, WH0, BA0) MFMA(aB0, WH0, BB0)
        MFMA(aA1, WH1, BA1) MFMA(aB1, WH1, BB1)
        MFMA(aA2, WH2, BA2) MFMA(aB2, WH2, BB2)
        MFMA(aA3, WH3, BA3) MFMA(aB3, WH3, BB3)
        MFMA(aA0, WL0, BA0) MFMA(aB0, WL0, BB0)
        MFMA(aA1, WL1, BA1) MFMA(aB1, WL1, BB1)
        MFMA(aA2, WL2, BA2) MFMA(aB2, WL2, BB2)
        MFMA(aA3, WL3, BA3) MFMA(aB3, WL3, BB3)

        const f32x4 sA = (aA0 + aA1) + (aA2 + aA3);
        const f32x4 sB = (aB0 + aB1) + (aB2 + aB3);
        hvA[0] = tanh_fast(sA[0]); hvA[1] = tanh_fast(sA[1]);
        hvA[2] = tanh_fast(sA[2]); hvA[3] = tanh_fast(sA[3]);
        hvB[0] = tanh_fast(sB[0]); hvB[1] = tanh_fast(sB[1]);
        hvB[2] = tanh_fast(sB[2]); hvB[3] = tanh_fast(sB[3]);

        *(uint2*)&lds[wbA + woff] =
            make_uint2(cvt_pk_bf16(hvA[0], hvA[1]), cvt_pk_bf16(hvA[2], hvA[3]));
        *(uint2*)&lds[wbA + 8192 + woff] =
            make_uint2(cvt_pk_bf16(hvB[0], hvB[1]), cvt_pk_bf16(hvB[2], hvB[3]));

        xtA = xnA; xtB = xnB;
        rbA ^= 4096; wbA ^= 4096;
        __syncthreads();
    }

    // ---- y = h_last . W_out + b_out, both seqs
    const float4 wo = *(const float4*)(W_out + j0);
    float vA = wo.x*hvA[0] + wo.y*hvA[1] + wo.z*hvA[2] + wo.w*hvA[3];
    float vB = wo.x*hvB[0] + wo.y*hvB[1] + wo.z*hvB[2] + wo.w*hvB[3];
    vA += __shfl_xor(vA, 16, 64); vA += __shfl_xor(vA, 32, 64);
    vB += __shfl_xor(vB, 16, 64); vB += __shfl_xor(vB, 32, 64);
    if (l < 16) {
        *(float*)&lds[16384 +       (w * 16 + r) * 4] = vA;
        *(float*)&lds[16384 + 512 + (w * 16 + r) * 4] = vB;
    }
    __syncthreads();
    if (tid < 32) {
        const int s  = tid >> 4, rr = tid & 15;
        float acc = 0.0f;
        #pragma unroll
        for (int ww = 0; ww < 8; ++ww)
            acc += *(const float*)&lds[16384 + s * 512 + (ww * 16 + rr) * 4];
        y[b0A + s * ROWS + rr] = acc + b_out[0];
    }
}

extern "C" void kernel_launch(void* const* d_in, const int* in_sizes, int n_in,
                              void* d_out, int out_size, void* d_ws, size_t ws_size,
                              hipStream_t stream)
{
    const float* x     = (const float*)d_in[0];
    const float* W_ih  = (const float*)d_in[1];
    const float* W_hh  = (const float*)d_in[2];
    const float* b_ih  = (const float*)d_in[3];
    const float* b_hh  = (const float*)d_in[4];
    const float* W_out = (const float*)d_in[5];
    const float* b_out = (const float*)d_in[6];
    float* y = (float*)d_out;

    const int B = in_sizes[0] / T_STEPS;   // 1024
    rnn_mfma8x2_kernel<<<B / (SEQS * ROWS), 512, 0, stream>>>(
        x, W_ih, W_hh, b_ih, b_hh, W_out, b_out, y);
}

// Round 15
// 215.116 us; speedup vs baseline: 1.6496x; 1.6496x over previous
//
#include <hip/hip_runtime.h>

#define T_STEPS 512
#define HID 128
#define ROWS 16   // batch rows per block -> 64 blocks

typedef short bf16x8 __attribute__((ext_vector_type(8)));   // MFMA A/B frag
typedef float f32x4  __attribute__((ext_vector_type(4)));   // MFMA C/D frag
typedef unsigned int u32;
typedef u32 u32x4 __attribute__((ext_vector_type(4)));

// R13 structure (199us) with ONE change: MFMA emitted as inline asm with "v"
// constraints, forcing A (weights), B, and acc into ArchVGPRs. R8-R14 data fit
// wall ~ 46.5cyc * MFMA/wave * waves/SIMD with weights homed in AGPRs
// (VGPR_Count=40!); uBench peak implies ~19.4cyc/SIMD throughput with VGPR
// operands. This round isolates the AGPR-source penalty.

__device__ __forceinline__ u32 cvt_pk_bf16(float s0, float s1) {
    u32 d;  // d.lo = bf16(s0), d.hi = bf16(s1)
    asm("v_cvt_pk_bf16_f32 %0, %1, %2" : "=v"(d) : "v"(s0), "v"(s1));
    return d;
}
__device__ __forceinline__ bf16x8 frag_from(u32 a, u32 b, u32 c, u32 d) {
    u32x4 t = {a, b, c, d};
    return __builtin_bit_cast(bf16x8, t);
}
// tanh(a) = 1 - 2/(exp2(2a*log2e)+1); saturates correctly at +-inf
__device__ __forceinline__ float tanh_fast(float a) {
    const float e  = __builtin_amdgcn_exp2f(a * 2.885390081777926816f);
    const float rc = __builtin_amdgcn_rcpf(e + 1.0f);
    return fmaf(-2.0f, rc, 1.0f);
}

// split 8 f32 into hi/lo bf16 frags (W ~= WH + WL, residual ~2^-18 rel)
#define SPLIT8(HI, LO, fa, fb) do {                                           \
    u32 h0_ = cvt_pk_bf16(fa.x,fa.y), h1_ = cvt_pk_bf16(fa.z,fa.w);           \
    u32 h2_ = cvt_pk_bf16(fb.x,fb.y), h3_ = cvt_pk_bf16(fb.z,fb.w);           \
    float l0_ = fa.x - __uint_as_float(h0_ << 16);                            \
    float l1_ = fa.y - __uint_as_float(h0_ & 0xffff0000u);                    \
    float l2_ = fa.z - __uint_as_float(h1_ << 16);                            \
    float l3_ = fa.w - __uint_as_float(h1_ & 0xffff0000u);                    \
    float l4_ = fb.x - __uint_as_float(h2_ << 16);                            \
    float l5_ = fb.y - __uint_as_float(h2_ & 0xffff0000u);                    \
    float l6_ = fb.z - __uint_as_float(h3_ << 16);                            \
    float l7_ = fb.w - __uint_as_float(h3_ & 0xffff0000u);                    \
    u32 g0_ = cvt_pk_bf16(l0_,l1_), g1_ = cvt_pk_bf16(l2_,l3_);               \
    u32 g2_ = cvt_pk_bf16(l4_,l5_), g3_ = cvt_pk_bf16(l6_,l7_);               \
    HI = frag_from(h0_,h1_,h2_,h3_); LO = frag_from(g0_,g1_,g2_,g3_);         \
} while (0)

// Inline-asm MFMA: forces ACC/A/B into ArchVGPRs ("v" constraints).
#define MFMA_V(ACC, A, B)                                                     \
    asm volatile("v_mfma_f32_16x16x32_bf16 %0, %1, %2, %0"                    \
                 : "+v"(ACC) : "v"(A), "v"(B));

// LDS: h buf0 @0, h buf1 @4096 ([16 r][128 j] bf16, byte ^= (r&7)<<4);
//      red @8192 ([8 w][16 r] f32)
#define LDS_BYTES (8192 + 512)

__global__ __launch_bounds__(512, 1)
__attribute__((amdgpu_waves_per_eu(2, 2)))
void rnn_mfma_v_kernel(const float* __restrict__ x,
                       const float* __restrict__ W_ih,
                       const float* __restrict__ W_hh,
                       const float* __restrict__ b_ih,
                       const float* __restrict__ b_hh,
                       const float* __restrict__ W_out,
                       const float* __restrict__ b_out,
                       float* __restrict__ y)
{
    __shared__ __align__(16) char lds[LDS_BYTES];

    const int tid = threadIdx.x;
    const int w   = tid >> 6;        // wave 0..7: j-tile [16w, 16w+16)
    const int l   = tid & 63;
    const int q   = l >> 4;          // lane quarter (k-group / C row group)
    const int r   = l & 15;          // batch row (A row m / B col n / C col n)
    const int b0  = blockIdx.x * ROWS;

    // ---- zero h buf0 (4 KB, 512 threads x 8 B)
    *(uint2*)&lds[tid * 8] = make_uint2(0u, 0u);

    // ---- W_hh A-frags for tile w: lane(q,r) holds A[m=r][k=32c+8q+e]
    bf16x8 WH0, WH1, WH2, WH3, WL0, WL1, WL2, WL3;
    {
        const float* p = W_hh + (size_t)(16 * w + r) * HID + 8 * q;
        float4 fa, fb;
        fa = *(const float4*)(p +  0); fb = *(const float4*)(p +   4); SPLIT8(WH0, WL0, fa, fb);
        fa = *(const float4*)(p + 32); fb = *(const float4*)(p +  36); SPLIT8(WH1, WL1, fa, fb);
        fa = *(const float4*)(p + 64); fb = *(const float4*)(p +  68); SPLIT8(WH2, WL2, fa, fb);
        fa = *(const float4*)(p + 96); fb = *(const float4*)(p + 100); SPLIT8(WH3, WL3, fa, fb);
    }

    // ---- per-lane constants for this lane's 4 outputs j0..j0+3
    const int j0 = 16 * w + 4 * q;
    const float4 wih = *(const float4*)(W_ih + j0);
    float4 bias;
    {
        const float4 bi = *(const float4*)(b_ih + j0);
        const float4 bh = *(const float4*)(b_hh + j0);
        bias.x = bi.x + bh.x; bias.y = bi.y + bh.y;
        bias.z = bi.z + bh.z; bias.w = bi.w + bh.w;
    }

    // ---- swizzled LDS offsets
    const int swz   = (r & 7) << 4;
    const int voff0 = (r*256 + q*16      ) ^ swz;   // B chunk 0
    const int voff1 = (r*256 + q*16 +  64) ^ swz;   // B chunk 1
    const int voff2 = (r*256 + q*16 + 128) ^ swz;   // B chunk 2
    const int voff3 = (r*256 + q*16 + 192) ^ swz;   // B chunk 3
    const int woff  = (r*256 + 32*w + 8*q) ^ swz;   // h write (8 B)

    const float* __restrict__ xrow = x + (size_t)(b0 + r) * T_STEPS;
    float xt = xrow[0];
    f32x4 hv;

    __syncthreads();

    u32 rb = 0, wb = 4096;
    for (int t = 0; t < T_STEPS; ++t) {
        bf16x8 B0 = *(const bf16x8*)&lds[rb + voff0];
        bf16x8 B1 = *(const bf16x8*)&lds[rb + voff1];
        bf16x8 B2 = *(const bf16x8*)&lds[rb + voff2];
        bf16x8 B3 = *(const bf16x8*)&lds[rb + voff3];
        const float xn = xrow[(t < T_STEPS - 1) ? t + 1 : T_STEPS - 1];

        f32x4 a0, a1, a2, a3;
        a0[0] = fmaf(xt, wih.x, bias.x); a0[1] = fmaf(xt, wih.y, bias.y);
        a0[2] = fmaf(xt, wih.z, bias.z); a0[3] = fmaf(xt, wih.w, bias.w);
        a1 = (f32x4)(0.0f); a2 = (f32x4)(0.0f); a3 = (f32x4)(0.0f);

        // VALU-write -> MFMA SrcC hazard guard (asm is opaque to the hazard
        // recognizer)
        asm volatile("s_nop 2");

        // 8 MFMAs, 4 independent chains of depth 2; all operands ArchVGPR
        MFMA_V(a0, WH0, B0) MFMA_V(a1, WH1, B1)
        MFMA_V(a2, WH2, B2) MFMA_V(a3, WH3, B3)
        MFMA_V(a0, WL0, B0) MFMA_V(a1, WL1, B1)
        MFMA_V(a2, WL2, B2) MFMA_V(a3, WL3, B3)

        // MFMA D -> VALU read guard
        asm volatile("s_nop 7\n\ts_nop 7");

        const f32x4 s = (a0 + a1) + (a2 + a3);
        hv[0] = tanh_fast(s[0]); hv[1] = tanh_fast(s[1]);
        hv[2] = tanh_fast(s[2]); hv[3] = tanh_fast(s[3]);

        *(uint2*)&lds[wb + woff] =
            make_uint2(cvt_pk_bf16(hv[0], hv[1]), cvt_pk_bf16(hv[2], hv[3]));

        xt = xn;
        rb ^= 4096; wb ^= 4096;
        __syncthreads();
    }

    // ---- y[b0+r] = sum_j W_out[j] * h_last[j] + b_out
    const float4 wo = *(const float4*)(W_out + j0);
    float v = wo.x*hv[0] + wo.y*hv[1] + wo.z*hv[2] + wo.w*hv[3];
    v += __shfl_xor(v, 16, 64);
    v += __shfl_xor(v, 32, 64);          // lane r: sum over this tile's 16 j
    if (l < 16) *(float*)&lds[8192 + (w * 16 + r) * 4] = v;
    __syncthreads();
    if (tid < 16) {
        float s = 0.0f;
        #pragma unroll
        for (int ww = 0; ww < 8; ++ww)
            s += *(const float*)&lds[8192 + (ww * 16 + tid) * 4];
        y[b0 + tid] = s + b_out[0];
    }
}

extern "C" void kernel_launch(void* const* d_in, const int* in_sizes, int n_in,
                              void* d_out, int out_size, void* d_ws, size_t ws_size,
                              hipStream_t stream)
{
    const float* x     = (const float*)d_in[0];
    const float* W_ih  = (const float*)d_in[1];
    const float* W_hh  = (const float*)d_in[2];
    const float* b_ih  = (const float*)d_in[3];
    const float* b_hh  = (const float*)d_in[4];
    const float* W_out = (const float*)d_in[5];
    const float* b_out = (const float*)d_in[6];
    float* y = (float*)d_out;

    const int B = in_sizes[0] / T_STEPS;   // 1024
    rnn_mfma_v_kernel<<<B / ROWS, 512, 0, stream>>>(x, W_ih, W_hh, b_ih, b_hh,
                                                    W_out, b_out, y);
}